// Round 1
// baseline (95.639 us; speedup 1.0000x reference)
//
#include <hip/hip_runtime.h>
#include <math.h>

// Problem geometry (fixed): B=4, N=16, K=16, H=64, O=1
// W: (a=16, b=16, d=16, e=16, k=16, o=64) fp32 = 256 MiB  -> memory-bound on W.
//
// h[z,a,o] = sum_{j=(b,d,e,k)} P[z,a,j] * W[a,j,o]
// P[z,a,j] = sum_c basis[z,a,b,k,c] * basis[z,d,e,k,c]
// out[z,a] = silu(h[z,a,:]) . w_fc + b_fc
//
// ws layout (floats):
//   basis : [4][16][16][16][3]          =    49,152 floats @ 0
//   P     : [16][65536][4] (float4)     = 4,194,304 floats @ 49,152   (byte off 196608, 16B aligned)
//   part  : [16][64][4*64]              =   262,144 floats @ 4,243,456
//   total ~18.0 MB (assumes ws_size >= 18,022,400 bytes)

#define NAT 16
#define NKR 16
#define NHID 64
#define NJ 65536
#define BPA 64  // blocks per 'a' in k_main

static constexpr double D_START = 0.006737946999085467; // exp(-5)

__global__ void k_basis(const float* __restrict__ x, float* __restrict__ basis) {
    int t = blockIdx.x * blockDim.x + threadIdx.x; // (z,p,q): 4*16*16 = 1024
    if (t >= 4 * NAT * NAT) return;
    int q = t & 15, p = (t >> 4) & 15, z = t >> 8;
    const float* xp = x + (z * NAT + p) * 3;
    const float* xq = x + (z * NAT + q) * 3;
    float d0 = xp[0] - xq[0], d1 = xp[1] - xq[1], d2 = xp[2] - xq[2];
    float nsq = d0 * d0 + d1 * d1 + d2 * d2 + 1e-5f;
    float nrm = sqrtf(nsq);
    // faithful to reference: diff /= norm^2
    float b0 = d0 / nsq, b1 = d1 / nsq, b2 = d2 / nsq;
    float cut = (nrm < 5.0f) ? 0.5f * (cosf(nrm * 0.6283185307179586f) + 1.0f) : 0.0f;
    float ex = expf(-nrm); // alpha=1, CUT_LO=0
    const float START = (float)D_START;
    const float STEP  = (float)((1.0 - D_START) / 15.0);
    const float BETA  = (float)(1.0 / ((0.125 * (1.0 - D_START)) * (0.125 * (1.0 - D_START))));
    float* o = basis + (size_t)t * NKR * 3;
    #pragma unroll
    for (int k = 0; k < NKR; ++k) {
        float m = START + STEP * (float)k;
        float dmm = ex - m;
        float s = cut * expf(-BETA * dmm * dmm);
        o[k * 3 + 0] = s * b0;
        o[k * 3 + 1] = s * b1;
        o[k * 3 + 2] = s * b2;
    }
}

__global__ void k_pmat(const float* __restrict__ basis, float4* __restrict__ P) {
    int t = blockIdx.x * 256 + threadIdx.x; // (a,j): 16*65536
    int a = t >> 16;
    int j = t & (NJ - 1);
    int b = (j >> 12) & 15, d = (j >> 8) & 15, e = (j >> 4) & 15, k = j & 15;
    float pv[4];
    #pragma unroll
    for (int z = 0; z < 4; ++z) {
        const float* u = basis + (((size_t)(z * 16 + a) * 16 + b) * 16 + k) * 3;
        const float* v = basis + (((size_t)(z * 16 + d) * 16 + e) * 16 + k) * 3;
        pv[z] = u[0] * v[0] + u[1] * v[1] + u[2] * v[2];
    }
    P[t] = make_float4(pv[0], pv[1], pv[2], pv[3]);
}

__global__ __launch_bounds__(256) void k_main(const float4* __restrict__ W4,
                                              const float4* __restrict__ P,
                                              float* __restrict__ part) {
    int a    = blockIdx.x / BPA;
    int blk  = blockIdx.x - a * BPA;
    int wave = threadIdx.x >> 6;
    int lane = threadIdx.x & 63;
    int og   = lane & 15;  // which group of 4 'o' columns
    int rsub = lane >> 4;  // row within the 4-row group
    int gbase = (blk * 4 + wave) * 64; // 64 groups per wave, contiguous

    float acc[4][4] = {{0.f, 0.f, 0.f, 0.f}, {0.f, 0.f, 0.f, 0.f},
                       {0.f, 0.f, 0.f, 0.f}, {0.f, 0.f, 0.f, 0.f}};
    size_t abase = (size_t)a * NJ;
    for (int g = 0; g < 64; ++g) {
        size_t row = abase + (size_t)((gbase + g) * 4 + rsub);
        float4 p4 = P[row];            // 16B, broadcast within 16-lane group (L1/L2)
        float4 w4 = W4[row * 16 + og]; // 16B/lane, wave covers 1KB contiguous HBM
        acc[0][0] += p4.x * w4.x; acc[0][1] += p4.x * w4.y; acc[0][2] += p4.x * w4.z; acc[0][3] += p4.x * w4.w;
        acc[1][0] += p4.y * w4.x; acc[1][1] += p4.y * w4.y; acc[1][2] += p4.y * w4.z; acc[1][3] += p4.y * w4.w;
        acc[2][0] += p4.z * w4.x; acc[2][1] += p4.z * w4.y; acc[2][2] += p4.z * w4.z; acc[2][3] += p4.z * w4.w;
        acc[3][0] += p4.w * w4.x; acc[3][1] += p4.w * w4.y; acc[3][2] += p4.w * w4.z; acc[3][3] += p4.w * w4.w;
    }
    // reduce across the 4 row-subgroups (lane bits 4,5)
    #pragma unroll
    for (int z = 0; z < 4; ++z) {
        #pragma unroll
        for (int c = 0; c < 4; ++c) {
            float v = acc[z][c];
            v += __shfl_xor(v, 16);
            v += __shfl_xor(v, 32);
            acc[z][c] = v;
        }
    }
    __shared__ float red[4][256];
    if (rsub == 0) {
        #pragma unroll
        for (int z = 0; z < 4; ++z) {
            #pragma unroll
            for (int c = 0; c < 4; ++c)
                red[wave][z * 64 + og * 4 + c] = acc[z][c];
        }
    }
    __syncthreads();
    int t = threadIdx.x; // (z*64 + o)
    float s = red[0][t] + red[1][t] + red[2][t] + red[3][t];
    part[((size_t)a * BPA + blk) * 256 + t] = s;
}

__global__ void k_out(const float* __restrict__ part, const float* __restrict__ w_fc,
                      const float* __restrict__ b_fc, float* __restrict__ out) {
    __shared__ float h[4096];
    int t = threadIdx.x;
    for (int i = t; i < 4096; i += 256) {
        int z = i >> 10, a = (i >> 6) & 15, o = i & 63;
        const float* p = part + ((size_t)a * BPA) * 256 + z * 64 + o;
        float s = 0.f;
        for (int blk = 0; blk < BPA; ++blk) s += p[(size_t)blk * 256];
        h[i] = s; // h[(z*16+a)*64+o] == h[i]
    }
    __syncthreads();
    if (t < 64) {
        int z = t >> 4, a = t & 15;
        float accv = 0.f;
        #pragma unroll
        for (int o = 0; o < NHID; ++o) {
            float hv = h[(z * 16 + a) * 64 + o];
            accv += hv * (1.0f / (1.0f + expf(-hv))) * w_fc[o]; // silu
        }
        out[t] = accv + b_fc[0];
    }
}

extern "C" void kernel_launch(void* const* d_in, const int* in_sizes, int n_in,
                              void* d_out, int out_size, void* d_ws, size_t ws_size,
                              hipStream_t stream) {
    const float* x    = (const float*)d_in[0];
    const float* W    = (const float*)d_in[1];
    const float* w_fc = (const float*)d_in[2];
    const float* b_fc = (const float*)d_in[3];
    float* ws = (float*)d_ws;

    float*  basis = ws;                                  // 49,152 floats
    float4* P     = (float4*)(ws + 49152);               // 4,194,304 floats
    float*  part  = ws + 49152 + (size_t)NAT * NJ * 4;   // 262,144 floats
    float*  out   = (float*)d_out;

    k_basis<<<4, 256, 0, stream>>>(x, basis);
    k_pmat<<<(NAT * NJ) / 256, 256, 0, stream>>>(basis, P);
    k_main<<<NAT * BPA, 256, 0, stream>>>((const float4*)W, P, part);
    k_out<<<1, 256, 0, stream>>>(part, w_fc, b_fc, out);
}

// Round 3
// 78.150 us; speedup vs baseline: 1.2238x; 1.2238x over previous
//
#include <hip/hip_runtime.h>
#include <math.h>

// Problem geometry (fixed): B=4, N=16, K=16, H=64, O=1
// W: (a=16, b=16, d=16, e=16, k=16, o=64) fp32 = 256 MiB  -> memory-bound on W.
//
// h[z,a,o] = sum_{j=(b,d,e,k)} P[z,a,j] * W[a,j,o]
// P[z,a,j] = sum_c basis[z,a,b,k,c] * basis[z,d,e,k,c]
// out[z,a] = silu(h[z,a,:]) . w_fc + b_fc
//
// ws layout (floats):
//   basis : [4][16][16][16][3]          =    49,152 floats @ 0
//   P     : [16][65536][4] (float4)     = 4,194,304 floats @ 49,152
//   part  : [16][128][4*64]             =   524,288 floats @ 4,243,456
//   total ~19.1 MB

#define NAT 16
#define NKR 16
#define NHID 64
#define NJ 65536
#define BPA 128  // blocks per 'a' in k_main -> 2048 blocks = 8 blocks/CU = 32 waves/CU

typedef float f32x4 __attribute__((ext_vector_type(4)));

static constexpr double D_START = 0.006737946999085467; // exp(-5)

__global__ void k_basis(const float* __restrict__ x, float* __restrict__ basis) {
    int t = blockIdx.x * blockDim.x + threadIdx.x; // (z,p,q): 4*16*16 = 1024
    if (t >= 4 * NAT * NAT) return;
    int q = t & 15, p = (t >> 4) & 15, z = t >> 8;
    const float* xp = x + (z * NAT + p) * 3;
    const float* xq = x + (z * NAT + q) * 3;
    float d0 = xp[0] - xq[0], d1 = xp[1] - xq[1], d2 = xp[2] - xq[2];
    float nsq = d0 * d0 + d1 * d1 + d2 * d2 + 1e-5f;
    float nrm = sqrtf(nsq);
    // faithful to reference: diff /= norm^2
    float b0 = d0 / nsq, b1 = d1 / nsq, b2 = d2 / nsq;
    float cut = (nrm < 5.0f) ? 0.5f * (cosf(nrm * 0.6283185307179586f) + 1.0f) : 0.0f;
    float ex = expf(-nrm); // alpha=1, CUT_LO=0
    const float START = (float)D_START;
    const float STEP  = (float)((1.0 - D_START) / 15.0);
    const float BETA  = (float)(1.0 / ((0.125 * (1.0 - D_START)) * (0.125 * (1.0 - D_START))));
    float* o = basis + (size_t)t * NKR * 3;
    #pragma unroll
    for (int k = 0; k < NKR; ++k) {
        float m = START + STEP * (float)k;
        float dmm = ex - m;
        float s = cut * expf(-BETA * dmm * dmm);
        o[k * 3 + 0] = s * b0;
        o[k * 3 + 1] = s * b1;
        o[k * 3 + 2] = s * b2;
    }
}

__global__ void k_pmat(const float* __restrict__ basis, f32x4* __restrict__ P) {
    int t = blockIdx.x * 256 + threadIdx.x; // (a,j): 16*65536
    int a = t >> 16;
    int j = t & (NJ - 1);
    int b = (j >> 12) & 15, d = (j >> 8) & 15, e = (j >> 4) & 15, k = j & 15;
    f32x4 pv;
    #pragma unroll
    for (int z = 0; z < 4; ++z) {
        const float* u = basis + (((size_t)(z * 16 + a) * 16 + b) * 16 + k) * 3;
        const float* v = basis + (((size_t)(z * 16 + d) * 16 + e) * 16 + k) * 3;
        pv[z] = u[0] * v[0] + u[1] * v[1] + u[2] * v[2];
    }
    P[t] = pv;
}

__global__ __launch_bounds__(256, 8) void k_main(const f32x4* __restrict__ W4,
                                                 const f32x4* __restrict__ P,
                                                 float* __restrict__ part) {
    int a    = blockIdx.x >> 7;       // blockIdx / BPA
    int blk  = blockIdx.x & (BPA - 1);
    int wave = threadIdx.x >> 6;
    int lane = threadIdx.x & 63;
    int og   = lane & 15;  // which group of 4 'o' columns
    int rsub = lane >> 4;  // row within the 4-row group
    int gbase = (blk * 4 + wave) * 32; // 32 groups per wave, contiguous

    float acc[4][4] = {{0.f, 0.f, 0.f, 0.f}, {0.f, 0.f, 0.f, 0.f},
                       {0.f, 0.f, 0.f, 0.f}, {0.f, 0.f, 0.f, 0.f}};
    size_t abase = (size_t)a * NJ;
    #pragma unroll 2
    for (int g = 0; g < 32; ++g) {
        size_t row = abase + (size_t)((gbase + g) * 4 + rsub);
        f32x4 p4 = P[row];             // 16B, broadcast within 16-lane group (L2-hot)
        f32x4 w4 = __builtin_nontemporal_load(&W4[row * 16 + og]); // streamed once
        acc[0][0] += p4.x * w4.x; acc[0][1] += p4.x * w4.y; acc[0][2] += p4.x * w4.z; acc[0][3] += p4.x * w4.w;
        acc[1][0] += p4.y * w4.x; acc[1][1] += p4.y * w4.y; acc[1][2] += p4.y * w4.z; acc[1][3] += p4.y * w4.w;
        acc[2][0] += p4.z * w4.x; acc[2][1] += p4.z * w4.y; acc[2][2] += p4.z * w4.z; acc[2][3] += p4.z * w4.w;
        acc[3][0] += p4.w * w4.x; acc[3][1] += p4.w * w4.y; acc[3][2] += p4.w * w4.z; acc[3][3] += p4.w * w4.w;
    }
    // reduce across the 4 row-subgroups (lane bits 4,5)
    #pragma unroll
    for (int z = 0; z < 4; ++z) {
        #pragma unroll
        for (int c = 0; c < 4; ++c) {
            float v = acc[z][c];
            v += __shfl_xor(v, 16);
            v += __shfl_xor(v, 32);
            acc[z][c] = v;
        }
    }
    __shared__ float red[4][256];
    if (rsub == 0) {
        #pragma unroll
        for (int z = 0; z < 4; ++z) {
            #pragma unroll
            for (int c = 0; c < 4; ++c)
                red[wave][z * 64 + og * 4 + c] = acc[z][c];
        }
    }
    __syncthreads();
    int t = threadIdx.x; // (z*64 + o)
    float s = red[0][t] + red[1][t] + red[2][t] + red[3][t];
    part[((size_t)a * BPA + blk) * 256 + t] = s;
}

__global__ void k_out(const float* __restrict__ part, const float* __restrict__ w_fc,
                      const float* __restrict__ b_fc, float* __restrict__ out) {
    // one block per (z,a); 256 threads = 4 blk-quarters x 64 'o'
    int z = blockIdx.x >> 4, a = blockIdx.x & 15;
    int o = threadIdx.x & 63, bq = threadIdx.x >> 6;
    float s = 0.f;
    for (int blk = bq; blk < BPA; blk += 4)
        s += part[((size_t)a * BPA + blk) * 256 + z * 64 + o]; // coalesced over o
    __shared__ float red[4][64];
    red[bq][o] = s;
    __syncthreads();
    if (threadIdx.x < 64) {
        float h = red[0][o] + red[1][o] + red[2][o] + red[3][o];
        float v = h * (1.0f / (1.0f + expf(-h))) * w_fc[o]; // silu * weight
        #pragma unroll
        for (int off = 32; off >= 1; off >>= 1) v += __shfl_xor(v, off);
        if (o == 0) out[z * 16 + a] = v + b_fc[0];
    }
}

extern "C" void kernel_launch(void* const* d_in, const int* in_sizes, int n_in,
                              void* d_out, int out_size, void* d_ws, size_t ws_size,
                              hipStream_t stream) {
    const float* x    = (const float*)d_in[0];
    const float* W    = (const float*)d_in[1];
    const float* w_fc = (const float*)d_in[2];
    const float* b_fc = (const float*)d_in[3];
    float* ws = (float*)d_ws;

    float*  basis = ws;                                  // 49,152 floats
    f32x4*  P     = (f32x4*)(ws + 49152);                // 4,194,304 floats
    float*  part  = ws + 49152 + (size_t)NAT * NJ * 4;   // 524,288 floats
    float*  out   = (float*)d_out;

    k_basis<<<4, 256, 0, stream>>>(x, basis);
    k_pmat<<<(NAT * NJ) / 256, 256, 0, stream>>>(basis, P);
    k_main<<<NAT * BPA, 256, 0, stream>>>((const f32x4*)W, P, part);
    k_out<<<64, 256, 0, stream>>>(part, w_fc, b_fc, out);
}